// Round 2
// baseline (278.696 us; speedup 1.0000x reference)
//
#include <hip/hip_runtime.h>
#include <stdint.h>

#define Bsz 16384
#define Hsz 256
#define K1 1024
#define N1 1536
#define K2 512
#define N2 512

typedef __bf16 bf16x8 __attribute__((ext_vector_type(8)));
typedef float f32x4 __attribute__((ext_vector_type(4)));

__device__ __forceinline__ unsigned short f2bf(float f) {
    union { float f; unsigned int u; } v; v.f = f;
    unsigned int u = v.u;
    unsigned int r = (u + 0x7fffu + ((u >> 16) & 1u)) >> 16;
    return (unsigned short)r;
}

__device__ __forceinline__ float sigm(float x) {
    return 1.0f / (1.0f + __expf(-x));
}

// ---------------- weight prep ----------------
// Wbig1 [1536][1024] bf16:
//   n in [0,768): re-output of gate g=(n%768)/256 (0=r,1=z,2=h1), j=n%256
//   n in [768,1536): im-output
//   k in [0,512): multiplies [x_re|h_re] ; k in [512,1024): multiplies [x_im|h_im]
__global__ void build_wbig1(const float* __restrict__ wr_re, const float* __restrict__ wr_im,
                            const float* __restrict__ wz_re, const float* __restrict__ wz_im,
                            const float* __restrict__ wh_re, const float* __restrict__ wh_im,
                            const float* __restrict__ ur_re, const float* __restrict__ ur_im,
                            const float* __restrict__ uz_re, const float* __restrict__ uz_im,
                            const float* __restrict__ uh_re, const float* __restrict__ uh_im,
                            unsigned short* __restrict__ wbig) {
    int idx = blockIdx.x * blockDim.x + threadIdx.x;
    if (idx >= N1 * K1) return;
    int n = idx / K1, k = idx % K1;
    int ng = n % 768;
    int g = ng / 256;
    int j = ng % 256;
    bool im_out = (n >= 768);
    bool second = (k >= 512);
    int kk = k & 511;
    const float *Wre, *Wim, *Ure, *Uim;
    if (g == 0)      { Wre = wr_re; Wim = wr_im; Ure = ur_re; Uim = ur_im; }
    else if (g == 1) { Wre = wz_re; Wim = wz_im; Ure = uz_re; Uim = uz_im; }
    else             { Wre = wh_re; Wim = wh_im; Ure = uh_re; Uim = uh_im; }
    float wre, wim;
    if (g < 2) {
        // r,z: W over [x|h] plus U over h
        wre = Wre[j * 512 + kk];
        wim = Wim[j * 512 + kk];
        if (kk >= 256) { wre += Ure[j * 256 + kk - 256]; wim += Uim[j * 256 + kk - 256]; }
    } else {
        // h1 (r-independent): x-part of Wh, then Uh over h
        if (kk < 256) { wre = Wre[j * 512 + kk];       wim = Wim[j * 512 + kk]; }
        else          { wre = Ure[j * 256 + kk - 256]; wim = Uim[j * 256 + kk - 256]; }
    }
    float val = (!im_out) ? (second ? -wim : wre) : (second ? wre : wim);
    wbig[idx] = f2bf(val);
}

// Wbig2 [512][512] bf16: rh-part of Wh.  wh2 = wh[:, 256:512]
__global__ void build_wbig2(const float* __restrict__ wh_re, const float* __restrict__ wh_im,
                            unsigned short* __restrict__ wbig2) {
    int idx = blockIdx.x * blockDim.x + threadIdx.x;
    if (idx >= N2 * K2) return;
    int n = idx / K2, k = idx % K2;
    int j = n & 255;
    bool im_out = (n >= 256);
    bool second = (k >= 256);
    int kk = k & 255;
    float wre = wh_re[j * 512 + 256 + kk];
    float wim = wh_im[j * 512 + 256 + kk];
    float val = (!im_out) ? (second ? -wim : wre) : (second ? wre : wim);
    wbig2[idx] = f2bf(val);
}

__global__ void build_bias(const float* __restrict__ br_re, const float* __restrict__ br_im,
                           const float* __restrict__ bz_re, const float* __restrict__ bz_im,
                           const float* __restrict__ bh_re, const float* __restrict__ bh_im,
                           float* __restrict__ bias) {
    int n = blockIdx.x * blockDim.x + threadIdx.x;
    if (n >= N1) return;
    int ng = n % 768;
    int g = ng / 256;
    int j = ng % 256;
    const float* re = (g == 0) ? br_re : ((g == 1) ? bz_re : bh_re);
    const float* im = (g == 0) ? br_im : ((g == 1) ? bz_im : bh_im);
    bias[n] = (n < 768) ? (re[j] - im[j]) : (re[j] + im[j]);
}

// ---------------- A builder: A = [x_re|h_re|x_im|h_im] bf16 [B, 1024] ----------------
__global__ void build_a(const float* __restrict__ xr, const float* __restrict__ hr,
                        const float* __restrict__ xi, const float* __restrict__ hi,
                        unsigned short* __restrict__ a) {
    int idx = blockIdx.x * blockDim.x + threadIdx.x;   // one per 4 elems
    if (idx >= Bsz * K1 / 4) return;
    int t = idx * 4;
    int b = t >> 10;
    int k = t & 1023;
    const float* src;
    int off;
    if (k < 256)      { src = xr; off = b * 256 + k; }
    else if (k < 512) { src = hr; off = b * 256 + k - 256; }
    else if (k < 768) { src = xi; off = b * 256 + k - 512; }
    else              { src = hi; off = b * 256 + k - 768; }
    f32x4 v = *(const f32x4*)(src + off);
    ushort4 o;
    o.x = f2bf(v[0]); o.y = f2bf(v[1]); o.z = f2bf(v[2]); o.w = f2bf(v[3]);
    *(ushort4*)(a + t) = o;
}

// ---------------- bf16 GEMM: C[M,N] = A[M,K] * Bm[N,K]^T (+bias[n]) ----------------
// 128x128 tile, BK=32, 256 threads (4 waves 2x2), mfma_f32_16x16x32_bf16.
// 1D grid, XCD-aware bijective swizzle (grid % 8 == 0 for all our launches).
template<int K, int NBX, bool HAS_BIAS>
__global__ __launch_bounds__(256)
void gemm_bt(const unsigned short* __restrict__ A,
             const unsigned short* __restrict__ Bm,
             const float* __restrict__ bias,
             float* __restrict__ C, int N) {
    __shared__ __align__(16) unsigned short sA[128 * 32];
    __shared__ __align__(16) unsigned short sB[128 * 32];
    const int tid  = threadIdx.x;
    const int lane = tid & 63;
    const int wid  = tid >> 6;

    // XCD swizzle: dispatch index round-robins XCDs; give each XCD a
    // contiguous chunk of work so same-row-panel blocks share an L2.
    const int nwg = gridDim.x;            // multiple of 8 by construction
    const int cpx = nwg >> 3;
    const int wgid = (blockIdx.x & 7) * cpx + (blockIdx.x >> 3);
    const int bx = wgid % NBX;            // col tile
    const int by = wgid / NBX;            // row tile
    const int rowA0 = by * 128;
    const int rowB0 = bx * 128;
    const int wm = (wid >> 1) * 64;
    const int wn = (wid & 1) * 64;

    f32x4 acc[4][4];
#pragma unroll
    for (int i = 0; i < 4; i++)
#pragma unroll
        for (int j = 0; j < 4; j++) acc[i][j] = {0.f, 0.f, 0.f, 0.f};

    const int segRow   = lane >> 2;   // 0..15 within a 1KB segment (16 rows)
    const int segChunk = lane & 3;    // 16B chunk within 64B row
    const int fr = lane & 15;
    const int fc = lane >> 4;         // 0..3

    for (int k0 = 0; k0 < K; k0 += 32) {
        __syncthreads();   // previous compute done before overwrite
#pragma unroll
        for (int i = 0; i < 2; i++) {
            int s = wid + i * 4;                 // segment 0..7
            int r = s * 16 + segRow;             // tile row
            const unsigned short* gp = A + (size_t)(rowA0 + r) * K + k0 + segChunk * 8;
            unsigned short* lp = sA + s * 512 + lane * 8;
            __builtin_amdgcn_global_load_lds((const __attribute__((address_space(1))) void*)gp,
                                             (__attribute__((address_space(3))) void*)lp,
                                             16, 0, 0);
        }
#pragma unroll
        for (int i = 0; i < 2; i++) {
            int s = wid + i * 4;
            int r = s * 16 + segRow;
            const unsigned short* gp = Bm + (size_t)(rowB0 + r) * K + k0 + segChunk * 8;
            unsigned short* lp = sB + s * 512 + lane * 8;
            __builtin_amdgcn_global_load_lds((const __attribute__((address_space(1))) void*)gp,
                                             (__attribute__((address_space(3))) void*)lp,
                                             16, 0, 0);
        }
        __syncthreads();   // staging complete (compiler drains vmcnt before barrier)

        bf16x8 af[4], bfr[4];
#pragma unroll
        for (int m = 0; m < 4; m++) {
            int r = wm + m * 16 + fr;
            af[m] = *(const bf16x8*)(sA + r * 32 + fc * 8);
        }
#pragma unroll
        for (int n = 0; n < 4; n++) {
            int r = wn + n * 16 + fr;
            bfr[n] = *(const bf16x8*)(sB + r * 32 + fc * 8);
        }
#pragma unroll
        for (int m = 0; m < 4; m++)
#pragma unroll
            for (int n = 0; n < 4; n++)
                acc[m][n] = __builtin_amdgcn_mfma_f32_16x16x32_bf16(af[m], bfr[n], acc[m][n], 0, 0, 0);
    }

    // epilogue: C/D layout col=lane&15, row=(lane>>4)*4+reg   [m89/m91 verified]
    const int crow = (lane >> 4) * 4;
    const int ccol = lane & 15;
#pragma unroll
    for (int m = 0; m < 4; m++) {
#pragma unroll
        for (int n = 0; n < 4; n++) {
            int gc = rowB0 + wn + n * 16 + ccol;
            float bv = HAS_BIAS ? bias[gc] : 0.f;
#pragma unroll
            for (int j = 0; j < 4; j++) {
                int gr = rowA0 + wm + m * 16 + crow + j;
                C[(size_t)gr * N + gc] = acc[m][n][j] + bv;
            }
        }
    }
}

// ---------------- r = sigmoid, rh = r*h (complex), A2 = [rh_re|rh_im] bf16 ----------------
__global__ void make_rh(const float* __restrict__ C1, const float* __restrict__ hr,
                        const float* __restrict__ hi, unsigned short* __restrict__ A2) {
    int idx = blockIdx.x * blockDim.x + threadIdx.x;   // per 4 cols
    if (idx >= Bsz * 64) return;
    int b = idx >> 6;
    int j = (idx & 63) * 4;
    const float* c = C1 + (size_t)b * N1;
    f32x4 ar  = *(const f32x4*)(c + j);          // r_re pre-act (cols 0..255)
    f32x4 ai  = *(const f32x4*)(c + 768 + j);    // r_im pre-act
    f32x4 hre = *(const f32x4*)(hr + b * 256 + j);
    f32x4 him = *(const f32x4*)(hi + b * 256 + j);
    unsigned short tre[4], tim[4];
#pragma unroll
    for (int t = 0; t < 4; t++) {
        float rr = sigm(ar[t]);
        float ri = sigm(ai[t]);
        tre[t] = f2bf(rr * hre[t] - ri * him[t]);
        tim[t] = f2bf(rr * him[t] + ri * hre[t]);
    }
    ushort4 ore, oim;
    ore.x = tre[0]; ore.y = tre[1]; ore.z = tre[2]; ore.w = tre[3];
    oim.x = tim[0]; oim.y = tim[1]; oim.z = tim[2]; oim.w = tim[3];
    *(ushort4*)(A2 + (size_t)b * 512 + j)       = ore;
    *(ushort4*)(A2 + (size_t)b * 512 + 256 + j) = oim;
}

// ---------------- final: z=sigmoid, hh=tanh(h1+h2), h_new ----------------
__global__ void finalize(const float* __restrict__ C1, const float* __restrict__ C2,
                         const float* __restrict__ hr, const float* __restrict__ hi,
                         float* __restrict__ out) {
    int idx = blockIdx.x * blockDim.x + threadIdx.x;   // per 4 cols
    if (idx >= Bsz * 64) return;
    int b = idx >> 6;
    int j = (idx & 63) * 4;
    const float* c1 = C1 + (size_t)b * N1;
    const float* c2 = C2 + (size_t)b * N2;
    f32x4 zr4 = *(const f32x4*)(c1 + 256 + j);
    f32x4 zi4 = *(const f32x4*)(c1 + 1024 + j);
    f32x4 h1r = *(const f32x4*)(c1 + 512 + j);
    f32x4 h1i = *(const f32x4*)(c1 + 1280 + j);
    f32x4 h2r = *(const f32x4*)(c2 + j);
    f32x4 h2i = *(const f32x4*)(c2 + 256 + j);
    f32x4 hre = *(const f32x4*)(hr + b * 256 + j);
    f32x4 him = *(const f32x4*)(hi + b * 256 + j);
    f32x4 outr, outi;
#pragma unroll
    for (int t = 0; t < 4; t++) {
        float zr = sigm(zr4[t]);
        float zi = sigm(zi4[t]);
        float hhr = tanhf(h1r[t] + h2r[t]);
        float hhi = tanhf(h1i[t] + h2i[t]);
        outr[t] = (1.f - zr) * hre[t] + zi * him[t] + zr * hhr - zi * hhi;
        outi[t] = (1.f - zr) * him[t] - zi * hre[t] + zr * hhi + zi * hhr;
    }
    *(f32x4*)(out + (size_t)b * 256 + j)                      = outr;
    *(f32x4*)(out + (size_t)Bsz * 256 + (size_t)b * 256 + j)  = outi;
}

extern "C" void kernel_launch(void* const* d_in, const int* in_sizes, int n_in,
                              void* d_out, int out_size, void* d_ws, size_t ws_size,
                              hipStream_t stream) {
    const float* x_re = (const float*)d_in[0];
    const float* x_im = (const float*)d_in[1];
    const float* h_re = (const float*)d_in[2];
    const float* h_im = (const float*)d_in[3];
    const float* wr_w_re = (const float*)d_in[4];
    const float* wr_w_im = (const float*)d_in[5];
    const float* wr_b_re = (const float*)d_in[6];
    const float* wr_b_im = (const float*)d_in[7];
    const float* wz_w_re = (const float*)d_in[8];
    const float* wz_w_im = (const float*)d_in[9];
    const float* wz_b_re = (const float*)d_in[10];
    const float* wz_b_im = (const float*)d_in[11];
    const float* wh_w_re = (const float*)d_in[12];
    const float* wh_w_im = (const float*)d_in[13];
    const float* wh_b_re = (const float*)d_in[14];
    const float* wh_b_im = (const float*)d_in[15];
    const float* ur_w_re = (const float*)d_in[16];
    const float* ur_w_im = (const float*)d_in[17];
    const float* uz_w_re = (const float*)d_in[18];
    const float* uz_w_im = (const float*)d_in[19];
    const float* uh_w_re = (const float*)d_in[20];
    const float* uh_w_im = (const float*)d_in[21];

    // Workspace layout (A2 aliases A_bf, dead after GEMM1). Total 171,448,320 B.
    char* ws = (char*)d_ws;
    unsigned short* W1    = (unsigned short*)(ws);                 //  3,145,728 B
    unsigned short* W2    = (unsigned short*)(ws + 3145728);       //    524,288 B
    float*          bias1 = (float*)         (ws + 3670016);       //      6,144 B
    unsigned short* A_bf  = (unsigned short*)(ws + 3676160);       // 33,554,432 B
    unsigned short* A2    = A_bf;                                  // alias (16,777,216 B)
    float*          C1    = (float*)         (ws + 37230592);      // 100,663,296 B
    float*          C2    = (float*)         (ws + 137893888);     // 33,554,432 B

    build_wbig1<<<(N1 * K1 + 255) / 256, 256, 0, stream>>>(
        wr_w_re, wr_w_im, wz_w_re, wz_w_im, wh_w_re, wh_w_im,
        ur_w_re, ur_w_im, uz_w_re, uz_w_im, uh_w_re, uh_w_im, W1);
    build_wbig2<<<(N2 * K2 + 255) / 256, 256, 0, stream>>>(wh_w_re, wh_w_im, W2);
    build_bias<<<(N1 + 255) / 256, 256, 0, stream>>>(
        wr_b_re, wr_b_im, wz_b_re, wz_b_im, wh_b_re, wh_b_im, bias1);
    build_a<<<(Bsz * K1 / 4 + 255) / 256, 256, 0, stream>>>(x_re, h_re, x_im, h_im, A_bf);

    gemm_bt<K1, N1 / 128, true><<<(N1 / 128) * (Bsz / 128), 256, 0, stream>>>(
        A_bf, W1, bias1, C1, N1);

    make_rh<<<(Bsz * 64 + 255) / 256, 256, 0, stream>>>(C1, h_re, h_im, A2);

    gemm_bt<K2, N2 / 128, false><<<(N2 / 128) * (Bsz / 128), 256, 0, stream>>>(
        A2, W2, nullptr, C2, N2);

    finalize<<<(Bsz * 64 + 255) / 256, 256, 0, stream>>>(C1, C2, h_re, h_im, (float*)d_out);
}